// Round 3
// baseline (45026.486 us; speedup 1.0000x reference)
//
#include <hip/hip_runtime.h>

#define B_ 64
#define T_ 256
#define F_ 512
#define H_ 1024
#define O_ 512
#define G3_ 3072
#define KS_ 8
#define NBLK 256

#define OUT_N   (T_ * B_ * O_)        /* 8388608 */
#define NSEL_IX OUT_N
#define SEL_OFF (OUT_N + 1)

// ---------------- device state (rewritten every call before use) ----------------
__device__ double g_WihT[(size_t)F_ * G3_];    // [k][col] f64 12.6 MB
__device__ double g_WhhT[(size_t)H_ * G3_];    // [k][col] f64 25.2 MB
__device__ double g_WselT[(size_t)H_ * F_];    // [k][f]   f64  4.2 MB
__device__ double g_bih[G3_];
__device__ double g_bhh[G3_];
__device__ double g_bsel[F_];
__device__ double g_h64[B_ * H_];              // current hidden (f64)
__device__ double g_ci64[B_ * F_];             // current masked input (f64)
__device__ double g_part[(size_t)KS_ * 4 * B_ * H_]; // [ks][ch][b][j] 16.8 MB
__device__ float  g_hist[(size_t)T_ * B_ * H_];// h history (f32), 67 MB
__device__ unsigned g_selcnt;
__device__ unsigned g_barcnt;

// ---------------- prep ----------------
__global__ void k_prep_wihT(const float* __restrict__ W) {
  int i = blockIdx.x * 256 + threadIdx.x;
  if (i < F_ * G3_) {
    int k = i / G3_, c = i % G3_;
    g_WihT[i] = (double)W[(size_t)c * F_ + k];
  }
}
__global__ void k_prep_whhT(const float* __restrict__ W) {
  int i = blockIdx.x * 256 + threadIdx.x;
  if (i < H_ * G3_) {
    int k = i / G3_, c = i % G3_;
    g_WhhT[i] = (double)W[(size_t)c * H_ + k];
  }
}
__global__ void k_prep_wselT(const float* __restrict__ W) {
  int i = blockIdx.x * 256 + threadIdx.x;
  if (i < H_ * F_) {
    int k = i / F_, f = i % F_;
    g_WselT[i] = (double)W[(size_t)f * H_ + k];
  }
}
__global__ void k_prep_misc(const float* __restrict__ x,
                            const float* __restrict__ bih,
                            const float* __restrict__ bhh,
                            const float* __restrict__ bsel,
                            float* __restrict__ out) {
  int i = blockIdx.x * 256 + threadIdx.x;   // 65536 threads
  if (i < B_ * H_) g_h64[i] = 0.0;
  if (i < B_ * F_) {
    int b = i >> 9, f = i & 511;
    g_ci64[i] = (double)x[(size_t)b * (T_ * F_) + f];  // t=0: curr_in = x_0
    out[(size_t)SEL_OFF + i] = 1.0f;                   // sel_weights[0] = ones
  }
  if (i < G3_) { g_bih[i] = (double)bih[i]; g_bhh[i] = (double)bhh[i]; }
  if (i < F_)  g_bsel[i] = (double)bsel[i];
  if (i == 0)  { g_selcnt = 0u; g_barcnt = 0u; }
}

// ---------------- grid barrier (all 256 blocks resident) ----------------
__device__ __forceinline__ void gridbar(unsigned target) {
  __syncthreads();                      // drains this block's stores (vmcnt 0)
  if (threadIdx.x == 0) {
    __threadfence();                    // release to device scope
    atomicAdd(&g_barcnt, 1u);
    while (__hip_atomic_load(&g_barcnt, __ATOMIC_RELAXED,
                             __HIP_MEMORY_SCOPE_AGENT) < target) {
      __builtin_amdgcn_s_sleep(1);
    }
    __threadfence();                    // acquire
  }
  __syncthreads();
}

// ---------------- the persistent time-loop kernel ----------------
// grid: 256 blocks x 512 threads. block -> G:(jc=bid>>3, ks=bid&7), L:(fc=bid>>3, bg=bid&7)
__global__ __launch_bounds__(512, 4) void k_persist(const float* __restrict__ x,
                                                    const float* __restrict__ u,
                                                    float* __restrict__ out) {
  const int tid = threadIdx.x;
  const int bid = blockIdx.x;
  const int jc  = bid >> 3;        // 0..31
  const int ks  = bid & 7;         // 0..7
  const int jl  = tid & 31;
  const int bq  = tid >> 5;        // 0..15
  const int b0g = bq << 2;         // gates: 4 b per thread
  const int j   = (jc << 5) + jl;  // hidden index 0..1023

  // L mapping
  const int fl  = tid & 15;
  const int kg  = tid >> 4;        // 0..31
  const int f   = jc * 16 + fl;    // fc == jc
  const int b0l = ks * 8;          // bg == ks

  __shared__ double lds[5664];
  double* s    = lds;              // gates staging: 32*66 = 2112
  double* shh  = lds;              // L h-stage: 8*130 = 1040
  double* red  = lds + 1040;       // L reduce: 32*16*9 = 4608 (ends 5648)

  const size_t chs = (size_t)B_ * H_;
  unsigned nbar = 0;

  for (int t = 0; t < T_; ++t) {
    // ================= L: logits(t-1) -> mask, ci(t), sel_weights[t] =================
    if (t > 0) {
      double acc[8];
      #pragma unroll
      for (int i = 0; i < 8; ++i) acc[i] = 0.0;
      #pragma unroll 1
      for (int c = 0; c < 8; ++c) {
        #pragma unroll
        for (int it = 0; it < 2; ++it) {
          int e  = it * 512 + tid;          // 0..1023
          int bb = e >> 7, kk = e & 127;
          shh[bb * 130 + kk] = g_h64[(size_t)(b0l + bb) * H_ + c * 128 + kk];
        }
        __syncthreads();
        const double* wp = &g_WselT[(size_t)(c * 128 + kg * 4) * F_ + f];
        #pragma unroll
        for (int ki = 0; ki < 4; ++ki) {
          double w = wp[0];
          wp += F_;
          #pragma unroll
          for (int bb = 0; bb < 8; ++bb)
            acc[bb] = fma(shh[bb * 130 + kg * 4 + ki], w, acc[bb]);
        }
        __syncthreads();
      }
      #pragma unroll
      for (int bb = 0; bb < 8; ++bb) red[(kg * 16 + fl) * 9 + bb] = acc[bb];
      __syncthreads();
      bool wflag = false;
      if (tid < 128) {
        int fl2 = tid & 15, bb2 = tid >> 4;
        double sum = 0.0;
        #pragma unroll
        for (int kk = 0; kk < 32; ++kk) sum += red[(kk * 16 + fl2) * 9 + bb2];
        int ff = jc * 16 + fl2;
        int bb = b0l + bb2;
        double logit = sum + g_bsel[ff];
        double sig = 1.0 / (1.0 + exp(-logit));
        float uv = u[(size_t)(t * B_ + bb) * F_ + ff];
        wflag = sig > (double)uv;
        out[(size_t)SEL_OFF + (size_t)(t * B_ + bb) * F_ + ff] = wflag ? 1.0f : 0.0f;
        g_ci64[bb * F_ + ff] = wflag ? (double)x[(size_t)(bb * T_ + t) * F_ + ff] : 0.0;
      }
      unsigned long long bal = __ballot(wflag);
      if (tid < 128 && (tid & 63) == 0) atomicAdd(&g_selcnt, (unsigned)__popcll(bal));
      __syncthreads();   // red/shh reads done before gates staging reuses lds
    }

    // ================= G: gates partial GEMM (f64, split-K) =================
    double ar0=0,ar1=0,ar2=0,ar3=0;
    double az0=0,az1=0,az2=0,az3=0;
    double ai0=0,ai1=0,ai2=0,ai3=0;   // i_n
    double ah0=0,ah1=0,ah2=0,ah3=0;   // h_n

    // ---- phase B first: gh over h(t-1), k in [ks*128, +128), 4 tiles
    #pragma unroll 1
    for (int kt = 0; kt < 4; ++kt) {
      const int kbase = ks * 128 + kt * 32;
      #pragma unroll
      for (int it = 0; it < 4; ++it) {
        int e  = it * 512 + tid;
        int kl = e & 31, bb = e >> 5;
        s[kl * 66 + bb] = g_h64[bb * H_ + kbase + kl];
      }
      __syncthreads();
      const double* wp = &g_WhhT[(size_t)kbase * G3_ + j];
      #pragma unroll 4
      for (int kl = 0; kl < 32; ++kl) {
        double wr = wp[0], wz = wp[H_], wn = wp[2 * H_];
        const double2* sp = (const double2*)&s[kl * 66 + b0g];
        double2 a01 = sp[0], a23 = sp[1];
        ar0 = fma(a01.x, wr, ar0); az0 = fma(a01.x, wz, az0); ah0 = fma(a01.x, wn, ah0);
        ar1 = fma(a01.y, wr, ar1); az1 = fma(a01.y, wz, az1); ah1 = fma(a01.y, wn, ah1);
        ar2 = fma(a23.x, wr, ar2); az2 = fma(a23.x, wz, az2); ah2 = fma(a23.x, wn, ah2);
        ar3 = fma(a23.y, wr, ar3); az3 = fma(a23.y, wz, az3); ah3 = fma(a23.y, wn, ah3);
        wp += G3_;
      }
      __syncthreads();
    }

    gridbar(++nbar * NBLK);   // alpha: ci(t) from L visible everywhere

    // ---- phase A: gi over ci(t), k in [ks*64, +64), 2 tiles
    #pragma unroll 1
    for (int kt = 0; kt < 2; ++kt) {
      const int kbase = ks * 64 + kt * 32;
      #pragma unroll
      for (int it = 0; it < 4; ++it) {
        int e  = it * 512 + tid;
        int kl = e & 31, bb = e >> 5;
        s[kl * 66 + bb] = g_ci64[bb * F_ + kbase + kl];
      }
      __syncthreads();
      const double* wp = &g_WihT[(size_t)kbase * G3_ + j];
      #pragma unroll 4
      for (int kl = 0; kl < 32; ++kl) {
        double wr = wp[0], wz = wp[H_], wn = wp[2 * H_];
        const double2* sp = (const double2*)&s[kl * 66 + b0g];
        double2 a01 = sp[0], a23 = sp[1];
        ar0 = fma(a01.x, wr, ar0); az0 = fma(a01.x, wz, az0); ai0 = fma(a01.x, wn, ai0);
        ar1 = fma(a01.y, wr, ar1); az1 = fma(a01.y, wz, az1); ai1 = fma(a01.y, wn, ai1);
        ar2 = fma(a23.x, wr, ar2); az2 = fma(a23.x, wz, az2); ai2 = fma(a23.x, wn, ai2);
        ar3 = fma(a23.y, wr, ar3); az3 = fma(a23.y, wz, az3); ai3 = fma(a23.y, wn, ai3);
        wp += G3_;
      }
      __syncthreads();
    }

    // ---- write partials: g_part[ks][ch][b][j]
    {
      size_t base = (size_t)ks * 4 * chs + (size_t)b0g * H_ + j;
      g_part[base + 0*H_]         = ar0;
      g_part[base + 1*H_]         = ar1;
      g_part[base + 2*H_]         = ar2;
      g_part[base + 3*H_]         = ar3;
      g_part[base + chs + 0*H_]   = az0;
      g_part[base + chs + 1*H_]   = az1;
      g_part[base + chs + 2*H_]   = az2;
      g_part[base + chs + 3*H_]   = az3;
      g_part[base + 2*chs + 0*H_] = ai0;
      g_part[base + 2*chs + 1*H_] = ai1;
      g_part[base + 2*chs + 2*H_] = ai2;
      g_part[base + 2*chs + 3*H_] = ai3;
      g_part[base + 3*chs + 0*H_] = ah0;
      g_part[base + 3*chs + 1*H_] = ah1;
      g_part[base + 3*chs + 2*H_] = ah2;
      g_part[base + 3*chs + 3*H_] = ah3;
    }

    gridbar(++nbar * NBLK);   // beta: partials visible

    // ================= R: reduce partials -> h(t) =================
    if (tid < 256) {
      int i = bid * 256 + tid;           // cell: b = i>>10, jj = i&1023
      int jj = i & 1023;
      double sr = 0.0, sz = 0.0, si = 0.0, sh2 = 0.0;
      #pragma unroll
      for (int kk = 0; kk < KS_; ++kk) {
        size_t base = (size_t)kk * 4 * chs + i;
        sr  += g_part[base];
        sz  += g_part[base + chs];
        si  += g_part[base + 2 * chs];
        sh2 += g_part[base + 3 * chs];
      }
      sr += g_bih[jj] + g_bhh[jj];
      sz += g_bih[H_ + jj] + g_bhh[H_ + jj];
      si += g_bih[2 * H_ + jj];
      sh2 += g_bhh[2 * H_ + jj];
      double r = 1.0 / (1.0 + exp(-sr));
      double z = 1.0 / (1.0 + exp(-sz));
      double n = tanh(si + r * sh2);
      double hnew = (1.0 - z) * n + z * g_h64[i];
      g_h64[i] = hnew;
      g_hist[(size_t)t * chs + i] = (float)hnew;
    }

    gridbar(++nbar * NBLK);   // gamma: h(t) visible
  }

  if (bid == 0 && tid == 0) out[NSEL_IX] = (float)g_selcnt;
}

// ---------------- batched out-GEMM (f32) ----------------
__global__ __launch_bounds__(256) void k_out(const float* __restrict__ Wo,
                                             const float* __restrict__ bo,
                                             float* __restrict__ out) {
  __shared__ float sA[32][68];
  __shared__ float sB[32][68];
  const int tid = threadIdx.x;
  const int to = tid & 15, tm = tid >> 4;
  const int m0 = blockIdx.y * 64, o0 = blockIdx.x * 64;
  float acc[4][4] = {{0.f}};
  for (int kt = 0; kt < 1024 / 32; ++kt) {
    #pragma unroll
    for (int it = 0; it < 8; ++it) {
      int e  = it * 256 + tid;
      int rl = e >> 5, kl = e & 31;
      sA[kl][rl] = g_hist[(size_t)(m0 + rl) * H_ + kt * 32 + kl];
      sB[kl][rl] = Wo[(size_t)(o0 + rl) * H_ + kt * 32 + kl];
    }
    __syncthreads();
    #pragma unroll
    for (int kl = 0; kl < 32; ++kl) {
      float a[4], bv[4];
      #pragma unroll
      for (int i = 0; i < 4; ++i) a[i] = sA[kl][tm * 4 + i];
      #pragma unroll
      for (int i = 0; i < 4; ++i) bv[i] = sB[kl][to * 4 + i];
      #pragma unroll
      for (int i = 0; i < 4; ++i)
        #pragma unroll
        for (int c = 0; c < 4; ++c)
          acc[i][c] = fmaf(a[i], bv[c], acc[i][c]);
    }
    __syncthreads();
  }
  #pragma unroll
  for (int i = 0; i < 4; ++i) {
    int m = m0 + tm * 4 + i;
    #pragma unroll
    for (int c = 0; c < 4; ++c) {
      int o = o0 + to * 4 + c;
      out[(size_t)m * O_ + o] = acc[i][c] + bo[o];
    }
  }
}

// ---------------- launcher ----------------
extern "C" void kernel_launch(void* const* d_in, const int* in_sizes, int n_in,
                              void* d_out, int out_size, void* d_ws, size_t ws_size,
                              hipStream_t stream) {
  (void)in_sizes; (void)n_in; (void)out_size; (void)d_ws; (void)ws_size;
  const float* x     = (const float*)d_in[0];
  const float* u     = (const float*)d_in[1];
  const float* W_ih  = (const float*)d_in[2];
  const float* b_ih  = (const float*)d_in[3];
  const float* W_hh  = (const float*)d_in[4];
  const float* b_hh  = (const float*)d_in[5];
  const float* W_out = (const float*)d_in[6];
  const float* b_out = (const float*)d_in[7];
  const float* W_sel = (const float*)d_in[8];
  const float* b_sel = (const float*)d_in[9];
  float* out = (float*)d_out;

  k_prep_wihT <<<(F_ * G3_ + 255) / 256, 256, 0, stream>>>(W_ih);
  k_prep_whhT <<<(H_ * G3_ + 255) / 256, 256, 0, stream>>>(W_hh);
  k_prep_wselT<<<(H_ * F_ + 255) / 256, 256, 0, stream>>>(W_sel);
  k_prep_misc <<<256, 256, 0, stream>>>(x, b_ih, b_hh, b_sel, out);

  k_persist<<<NBLK, 512, 0, stream>>>(x, u, out);

  k_out<<<dim3(8, 256), 256, 0, stream>>>(W_out, b_out, out);
}

// Round 4
// 38994.614 us; speedup vs baseline: 1.1547x; 1.1547x over previous
//
#include <hip/hip_runtime.h>

#define B_ 64
#define T_ 256
#define F_ 512
#define H_ 1024
#define O_ 512
#define KS_ 8
#define NBLK 256
#define NTHR 1024

#define OUT_N   (T_ * B_ * O_)        /* 8388608 */
#define NSEL_IX OUT_N
#define SEL_OFF (OUT_N + 1)

// ---------------- device state (rewritten every call before use) ----------------
__device__ float2 g_ihrz[(size_t)F_ * H_];   // [k][j] (r,z) packed, 4.2 MB
__device__ float  g_ihn [(size_t)F_ * H_];   // [k][j] n, 2.1 MB
__device__ float2 g_hhrz[(size_t)H_ * H_];   // [k][j], 8.4 MB
__device__ float  g_hhn [(size_t)H_ * H_];   // [k][j], 4.2 MB
__device__ float  g_wsel[(size_t)H_ * F_];   // [k][f], 2.1 MB
__device__ double g_bih[3 * H_];
__device__ double g_bhh[3 * H_];
__device__ double g_bsel[F_];
__device__ double g_h64[B_ * H_];            // coherent (sc1) traffic only
__device__ double g_ci64[B_ * F_];           // coherent
__device__ double g_part[(size_t)KS_ * 4 * B_ * H_];  // coherent, 16.8 MB
__device__ float  g_hist[(size_t)T_ * B_ * H_];       // plain, 67 MB
__device__ unsigned g_selcnt;
__device__ unsigned g_barcnt;

// ---------------- coherent (cross-XCD, L2-bypass) access helpers ----------------
__device__ __forceinline__ double ld_c(const double* p) {
  return __hip_atomic_load(p, __ATOMIC_RELAXED, __HIP_MEMORY_SCOPE_AGENT);
}
__device__ __forceinline__ void st_c(double* p, double v) {
  __hip_atomic_store(p, v, __ATOMIC_RELAXED, __HIP_MEMORY_SCOPE_AGENT);
}
__device__ __forceinline__ double sx(double v, int m) { return __shfl_xor(v, m, 64); }

// ---------------- prep ----------------
__global__ void k_prep_ih(const float* __restrict__ W) {   // W_ih [3H, F]
  int i = blockIdx.x * 256 + threadIdx.x;
  if (i < F_ * H_) {
    int k = i >> 10, j = i & 1023;
    g_ihrz[i] = make_float2(W[(size_t)j * F_ + k], W[(size_t)(H_ + j) * F_ + k]);
    g_ihn[i]  = W[(size_t)(2 * H_ + j) * F_ + k];
  }
}
__global__ void k_prep_hh(const float* __restrict__ W) {   // W_hh [3H, H]
  int i = blockIdx.x * 256 + threadIdx.x;
  if (i < H_ * H_) {
    int k = i >> 10, j = i & 1023;
    g_hhrz[i] = make_float2(W[(size_t)j * H_ + k], W[(size_t)(H_ + j) * H_ + k]);
    g_hhn[i]  = W[(size_t)(2 * H_ + j) * H_ + k];
  }
}
__global__ void k_prep_wsel(const float* __restrict__ W) { // W_sel [F, H]
  int i = blockIdx.x * 256 + threadIdx.x;
  if (i < H_ * F_) {
    int k = i >> 9, f = i & 511;
    g_wsel[i] = W[(size_t)f * H_ + k];
  }
}
__global__ void k_prep_misc(const float* __restrict__ x,
                            const float* __restrict__ bih,
                            const float* __restrict__ bhh,
                            const float* __restrict__ bsel,
                            float* __restrict__ out) {
  int i = blockIdx.x * 256 + threadIdx.x;   // 65536
  if (i < B_ * H_) g_h64[i] = 0.0;
  if (i < B_ * F_) {
    int b = i >> 9, f = i & 511;
    g_ci64[i] = (double)x[(size_t)b * (T_ * F_) + f];  // t=0: curr_in = x_0
    out[(size_t)SEL_OFF + i] = 1.0f;                   // sel_weights[0] = ones
  }
  if (i < 3 * H_) { g_bih[i] = (double)bih[i]; g_bhh[i] = (double)bhh[i]; }
  if (i < F_)  g_bsel[i] = (double)bsel[i];
  if (i == 0)  { g_selcnt = 0u; g_barcnt = 0u; }
}

// ---------------- grid barrier: NO fences (keeps L2 warm). ----------------
// Safety: __syncthreads() drains this block's vmcnt (sc1 stores complete at the
// coherence point) before the counter add; readers' data loads are issued after
// the spin exits (control dependence) and are themselves sc1.
__device__ __forceinline__ void gridbar(unsigned target) {
  __syncthreads();
  if (threadIdx.x == 0) {
    __hip_atomic_fetch_add(&g_barcnt, 1u, __ATOMIC_RELAXED, __HIP_MEMORY_SCOPE_AGENT);
    while (__hip_atomic_load(&g_barcnt, __ATOMIC_RELAXED, __HIP_MEMORY_SCOPE_AGENT) < target)
      __builtin_amdgcn_s_sleep(2);
  }
  __syncthreads();
}

// ---------------- G-phase macros ----------------
#define G_STAGE(SRC0CI, KB0, KB1)                                              \
  { _Pragma("unroll")                                                          \
    for (int it_ = 0; it_ < 4; ++it_) {                                        \
      const int cidx_ = it_ >> 1;                                              \
      const int elem_ = ((it_ & 1) << 10) + tid;                               \
      const int kl_ = elem_ & 31, bb_ = elem_ >> 5;                            \
      double v_;                                                               \
      if (cidx_ == 0) v_ = (SRC0CI) ? ld_c(&g_ci64[(size_t)bb_ * F_ + (KB0) + kl_]) \
                                    : ld_c(&g_h64 [(size_t)bb_ * H_ + (KB0) + kl_]); \
      else            v_ = ld_c(&g_h64[(size_t)bb_ * H_ + (KB1) + kl_]);       \
      lds[cidx_ * 2112 + kl_ * 66 + bb_] = v_;                                 \
    } }

#define G_COMP(KB0, KB1, IHOK, ANa, ANb, ANc, ANd)                             \
  { const int kb_ = kh ? (KB1) : (KB0);                                        \
    const bool isih_ = (IHOK) && !kh;                                          \
    const float2* rzp_ = (isih_ ? g_ihrz : g_hhrz) + (size_t)kb_ * H_ + j;     \
    const float*  nnp_ = (isih_ ? g_ihn  : g_hhn ) + (size_t)kb_ * H_ + j;     \
    const double* sp_ = &lds[kh * 2112 + b0];                                  \
    _Pragma("unroll 4")                                                        \
    for (int kl_ = 0; kl_ < 32; ++kl_) {                                       \
      float2 w2_ = rzp_[(size_t)kl_ * H_];                                     \
      float  w1_ = nnp_[(size_t)kl_ * H_];                                     \
      double wr_ = (double)w2_.x, wz_ = (double)w2_.y, wn_ = (double)w1_;      \
      const double2 a01_ = *(const double2*)(sp_ + kl_ * 66);                  \
      const double2 a23_ = *(const double2*)(sp_ + kl_ * 66 + 2);              \
      ar0 = fma(a01_.x, wr_, ar0); az0 = fma(a01_.x, wz_, az0); ANa = fma(a01_.x, wn_, ANa); \
      ar1 = fma(a01_.y, wr_, ar1); az1 = fma(a01_.y, wz_, az1); ANb = fma(a01_.y, wn_, ANb); \
      ar2 = fma(a23_.x, wr_, ar2); az2 = fma(a23_.x, wz_, az2); ANc = fma(a23_.x, wn_, ANc); \
      ar3 = fma(a23_.y, wr_, ar3); az3 = fma(a23_.y, wz_, az3); ANd = fma(a23_.y, wn_, ANd); \
    } }

// ---------------- the persistent time-loop kernel ----------------
// grid 256 x 1024. LDS 88KB forces exactly 1 block/CU -> co-residency guaranteed.
__global__ __launch_bounds__(NTHR, 4) void k_persist(const float* __restrict__ x,
                                                     const float* __restrict__ u,
                                                     float* __restrict__ out) {
  __shared__ double lds[11000];   // 88 KB
  const int tid = threadIdx.x;
  const int bid = blockIdx.x;
  const int jc  = bid >> 3;        // 0..31
  const int ks  = bid & 7;         // 0..7  (== XCD id under % 8 round-robin)
  // G decode: thread = (jl, kh, bq); wave: lanes 0-31 kh=0, 32-63 kh=1
  const int jl = tid & 31;
  const int kh = (tid >> 5) & 1;
  const int bq = tid >> 6;         // 0..15
  const int b0 = bq << 2;          // 4 b per thread
  const int j  = (jc << 5) + jl;
  // L decode: thread = (fl, kgl, lbb, kgh)
  const int fl  = tid & 15;
  const int kgl = (tid >> 4) & 3;
  const int lbb = (tid >> 6) & 7;
  const int kgh = tid >> 9;
  const int kg  = kgl | (kgh << 2);   // 0..7, 128 k each
  const int f   = (jc << 4) + fl;
  const int b0l = ks << 3;
  // R decode
  const int ri  = bid * 256 + (tid & 255);
  const int rjj = ri & 1023;
  double bs_r = 0, bs_z = 0, bs_i = 0, bs_h = 0, bsel_f = 0;
  if (tid < 256) {
    bs_r = g_bih[rjj] + g_bhh[rjj];
    bs_z = g_bih[H_ + rjj] + g_bhh[H_ + rjj];
    bs_i = g_bih[2 * H_ + rjj];
    bs_h = g_bhh[2 * H_ + rjj];
  }
  bsel_f = g_bsel[f];

  const size_t chs = (size_t)B_ * H_;
  unsigned nbar = 0;

  for (int t = 0; t < T_; ++t) {
    // ================= L: logits(h(t-1)) -> mask, ci(t), sel_weights[t] ==========
    if (t > 0) {
      #pragma unroll
      for (int it = 0; it < 8; ++it)
        lds[it * 1026 + tid] = ld_c(&g_h64[(size_t)(b0l + it) * H_ + tid]);
      __syncthreads();
      double acc = 0.0;
      const int k0 = kg << 7;
      const int rot = kg << 2;
      #pragma unroll 4
      for (int ki = 0; ki < 128; ++ki) {
        int kk = (ki + rot) & 127;
        acc = fma(lds[lbb * 1026 + k0 + kk], (double)g_wsel[(size_t)(k0 + kk) * F_ + f], acc);
      }
      acc += sx(acc, 16);
      acc += sx(acc, 32);               // lanes kgl==0 hold partial (fl, lbb, kgh)
      if (kgh && kgl == 0) lds[8208 + lbb * 16 + fl] = acc;
      __syncthreads();
      bool wflag = false;
      if (!kgh && kgl == 0) {
        double s = acc + lds[8208 + lbb * 16 + fl];
        double logit = s + bsel_f;
        double sig = 1.0 / (1.0 + exp(-logit));
        int b = b0l + lbb;
        float uv = u[(size_t)(t * B_ + b) * F_ + f];
        wflag = sig > (double)uv;
        out[(size_t)SEL_OFF + (size_t)(t * B_ + b) * F_ + f] = wflag ? 1.0f : 0.0f;
        st_c(&g_ci64[b * F_ + f], wflag ? (double)x[(size_t)(b * T_ + t) * F_ + f] : 0.0);
      }
      unsigned long long bal = __ballot(wflag);
      if (!kgh && (tid & 63) == 0) atomicAdd(&g_selcnt, (unsigned)__popcll(bal));
      __syncthreads();
    }

    gridbar(++nbar * NBLK);   // alpha: ci(t) visible everywhere; h(t-1) stable

    // ================= G: gates, split-K across blocks (ks), kh-split in block ===
    double ar0=0,ar1=0,ar2=0,ar3=0;
    double az0=0,az1=0,az2=0,az3=0;
    double aA0=0,aA1=0,aA2=0,aA3=0;   // kh0: i_n (ih);      kh1: h_n part 1
    double aB0=0,aB1=0,aB2=0,aB3=0;   // kh0: h_n (hh SI2);  kh1: h_n part 2

    // SI0: kh0 <- ci[ks*64..+32) (ih), kh1 <- h[ks*128+32..+32) (hh)
    G_STAGE(1, ks * 64, ks * 128 + 32)
    __syncthreads();
    G_COMP(ks * 64, ks * 128 + 32, true, aA0, aA1, aA2, aA3)
    __syncthreads();
    // SI1: kh0 <- ci[+32..64) (ih), kh1 <- h[+64..96) (hh)
    G_STAGE(1, ks * 64 + 32, ks * 128 + 64)
    __syncthreads();
    G_COMP(ks * 64 + 32, ks * 128 + 64, true, aA0, aA1, aA2, aA3)
    __syncthreads();
    // SI2: kh0 <- h[+0..32) (hh), kh1 <- h[+96..128) (hh)
    G_STAGE(0, ks * 128, ks * 128 + 96)
    __syncthreads();
    G_COMP(ks * 128, ks * 128 + 96, false, aB0, aB1, aB2, aB3)

    // combine kh halves: r,z straight sums; in = kh0's aA; hn = kh0's aB + kh1's (aA+aB)
    double in0 = kh ? 0.0 : aA0, in1 = kh ? 0.0 : aA1, in2 = kh ? 0.0 : aA2, in3 = kh ? 0.0 : aA3;
    double hn0 = kh ? (aA0 + aB0) : aB0, hn1 = kh ? (aA1 + aB1) : aB1;
    double hn2 = kh ? (aA2 + aB2) : aB2, hn3 = kh ? (aA3 + aB3) : aB3;
    ar0 += sx(ar0, 32); ar1 += sx(ar1, 32); ar2 += sx(ar2, 32); ar3 += sx(ar3, 32);
    az0 += sx(az0, 32); az1 += sx(az1, 32); az2 += sx(az2, 32); az3 += sx(az3, 32);
    in0 += sx(in0, 32); in1 += sx(in1, 32); in2 += sx(in2, 32); in3 += sx(in3, 32);
    hn0 += sx(hn0, 32); hn1 += sx(hn1, 32); hn2 += sx(hn2, 32); hn3 += sx(hn3, 32);

    {
      size_t pb = (size_t)ks * 4 * chs + (size_t)b0 * H_ + j;
      if (!kh) {
        st_c(&g_part[pb + 0 * H_], ar0); st_c(&g_part[pb + 1 * H_], ar1);
        st_c(&g_part[pb + 2 * H_], ar2); st_c(&g_part[pb + 3 * H_], ar3);
        st_c(&g_part[pb + chs + 0 * H_], az0); st_c(&g_part[pb + chs + 1 * H_], az1);
        st_c(&g_part[pb + chs + 2 * H_], az2); st_c(&g_part[pb + chs + 3 * H_], az3);
      } else {
        st_c(&g_part[pb + 2 * chs + 0 * H_], in0); st_c(&g_part[pb + 2 * chs + 1 * H_], in1);
        st_c(&g_part[pb + 2 * chs + 2 * H_], in2); st_c(&g_part[pb + 2 * chs + 3 * H_], in3);
        st_c(&g_part[pb + 3 * chs + 0 * H_], hn0); st_c(&g_part[pb + 3 * chs + 1 * H_], hn1);
        st_c(&g_part[pb + 3 * chs + 2 * H_], hn2); st_c(&g_part[pb + 3 * chs + 3 * H_], hn3);
      }
    }

    gridbar(++nbar * NBLK);   // beta: partials visible

    // ================= R: reduce partials -> h(t) =================
    if (tid < 256) {
      double sr = bs_r, szv = bs_z, si = bs_i, sh2 = bs_h;
      #pragma unroll
      for (int kk = 0; kk < KS_; ++kk) {
        size_t base = (size_t)kk * 4 * chs + ri;
        sr  += ld_c(&g_part[base]);
        szv += ld_c(&g_part[base + chs]);
        si  += ld_c(&g_part[base + 2 * chs]);
        sh2 += ld_c(&g_part[base + 3 * chs]);
      }
      double r = 1.0 / (1.0 + exp(-sr));
      double z = 1.0 / (1.0 + exp(-szv));
      double n = tanh(si + r * sh2);
      double hnew = (1.0 - z) * n + z * ld_c(&g_h64[ri]);
      st_c(&g_h64[ri], hnew);
      g_hist[(size_t)t * chs + ri] = (float)hnew;
    }

    gridbar(++nbar * NBLK);   // gamma: h(t) visible
  }

  if (bid == 0 && tid == 0)
    out[NSEL_IX] = (float)__hip_atomic_load(&g_selcnt, __ATOMIC_RELAXED, __HIP_MEMORY_SCOPE_AGENT);
}

// ---------------- batched out-GEMM (f32) ----------------
__global__ __launch_bounds__(256) void k_out(const float* __restrict__ Wo,
                                             const float* __restrict__ bo,
                                             float* __restrict__ out) {
  __shared__ float sA[32][68];
  __shared__ float sB[32][68];
  const int tid = threadIdx.x;
  const int to = tid & 15, tm = tid >> 4;
  const int m0 = blockIdx.y * 64, o0 = blockIdx.x * 64;
  float acc[4][4] = {{0.f}};
  for (int kt = 0; kt < 1024 / 32; ++kt) {
    #pragma unroll
    for (int it = 0; it < 8; ++it) {
      int e  = it * 256 + tid;
      int rl = e >> 5, kl = e & 31;
      sA[kl][rl] = g_hist[(size_t)(m0 + rl) * H_ + kt * 32 + kl];
      sB[kl][rl] = Wo[(size_t)(o0 + rl) * H_ + kt * 32 + kl];
    }
    __syncthreads();
    #pragma unroll
    for (int kl = 0; kl < 32; ++kl) {
      float a[4], bv[4];
      #pragma unroll
      for (int i = 0; i < 4; ++i) a[i] = sA[kl][tm * 4 + i];
      #pragma unroll
      for (int i = 0; i < 4; ++i) bv[i] = sB[kl][to * 4 + i];
      #pragma unroll
      for (int i = 0; i < 4; ++i)
        #pragma unroll
        for (int c = 0; c < 4; ++c)
          acc[i][c] = fmaf(a[i], bv[c], acc[i][c]);
    }
    __syncthreads();
  }
  #pragma unroll
  for (int i = 0; i < 4; ++i) {
    int m = m0 + tm * 4 + i;
    #pragma unroll
    for (int c = 0; c < 4; ++c) {
      int o = o0 + to * 4 + c;
      out[(size_t)m * O_ + o] = acc[i][c] + bo[o];
    }
  }
}

// ---------------- launcher ----------------
extern "C" void kernel_launch(void* const* d_in, const int* in_sizes, int n_in,
                              void* d_out, int out_size, void* d_ws, size_t ws_size,
                              hipStream_t stream) {
  (void)in_sizes; (void)n_in; (void)out_size; (void)d_ws; (void)ws_size;
  const float* x     = (const float*)d_in[0];
  const float* u     = (const float*)d_in[1];
  const float* W_ih  = (const float*)d_in[2];
  const float* b_ih  = (const float*)d_in[3];
  const float* W_hh  = (const float*)d_in[4];
  const float* b_hh  = (const float*)d_in[5];
  const float* W_out = (const float*)d_in[6];
  const float* b_out = (const float*)d_in[7];
  const float* W_sel = (const float*)d_in[8];
  const float* b_sel = (const float*)d_in[9];
  float* out = (float*)d_out;

  k_prep_ih  <<<(F_ * H_ + 255) / 256, 256, 0, stream>>>(W_ih);
  k_prep_hh  <<<(H_ * H_ + 255) / 256, 256, 0, stream>>>(W_hh);
  k_prep_wsel<<<(H_ * F_ + 255) / 256, 256, 0, stream>>>(W_sel);
  k_prep_misc<<<256, 256, 0, stream>>>(x, b_ih, b_hh, b_sel, out);

  k_persist<<<NBLK, NTHR, 0, stream>>>(x, u, out);

  k_out<<<dim3(8, 256), 256, 0, stream>>>(W_out, b_out, out);
}

// Round 5
// 25489.156 us; speedup vs baseline: 1.7665x; 1.5299x over previous
//
#include <hip/hip_runtime.h>

#define B_ 64
#define T_ 256
#define F_ 512
#define H_ 1024
#define O_ 512
#define NBLK 256
#define NTHR 1024

#define OUT_N   (T_ * B_ * O_)        /* 8388608 */
#define NSEL_IX OUT_N
#define SEL_OFF (OUT_N + 1)

// LDS map (doubles): act tiles padded to stride 10
#define ACI 0                 /* ci tile  [512][10]  */
#define AH  5120              /* h tile   [1024][10] */
#define LDS_N 15360           /* 122.9 KB -> 1 block/CU */

// ---------------- device state ----------------
__device__ float2 g_Wrz[(size_t)1536 * 1024];   // [k][jj] (r,z) f32, 12.6 MB
__device__ float  g_Wn [(size_t)1536 * 1024];   // [k][jj] n f32,     6.3 MB
__device__ double g_wselT[(size_t)H_ * F_];     // [k][f] f64,        4.2 MB
__device__ double g_br[H_], g_bz[H_], g_bi[H_], g_bh[H_];
__device__ double g_bsel[F_];
__device__ double g_h64[B_ * H_];               // sc1-only traffic
__device__ double g_ci64[B_ * F_];              // sc1-only traffic
__device__ float  g_hist[(size_t)T_ * B_ * H_]; // plain, 67 MB
__device__ unsigned g_selcnt;
__device__ unsigned g_bar8[128];                // 8 counters, 64B apart

// ---------------- coherent access helpers ----------------
__device__ __forceinline__ double ld_c(const double* p) {
  return __hip_atomic_load(p, __ATOMIC_RELAXED, __HIP_MEMORY_SCOPE_AGENT);
}
__device__ __forceinline__ void st_c(double* p, double v) {
  __hip_atomic_store(p, v, __ATOMIC_RELAXED, __HIP_MEMORY_SCOPE_AGENT);
}

// ---------------- prep ----------------
__global__ void k_prep_w(const float* __restrict__ Wih, const float* __restrict__ Whh) {
  int i = blockIdx.x * 256 + threadIdx.x;      // 1536*1024
  int k = i >> 10, jj = i & 1023;
  float r, z, n;
  if (k < 512) {
    r = Wih[(size_t)jj * F_ + k];
    z = Wih[(size_t)(H_ + jj) * F_ + k];
    n = Wih[(size_t)(2 * H_ + jj) * F_ + k];
  } else {
    int kk = k - 512;
    r = Whh[(size_t)jj * H_ + kk];
    z = Whh[(size_t)(H_ + jj) * H_ + kk];
    n = Whh[(size_t)(2 * H_ + jj) * H_ + kk];
  }
  g_Wrz[i] = make_float2(r, z);
  g_Wn[i]  = n;
}
__global__ void k_prep_wsel(const float* __restrict__ W) {  // W_sel [F, H]
  int i = blockIdx.x * 256 + threadIdx.x;      // 1024*512
  int k = i >> 9, f = i & 511;
  g_wselT[i] = (double)W[(size_t)f * H_ + k];
}
__global__ void k_prep_misc(const float* __restrict__ x,
                            const float* __restrict__ bih,
                            const float* __restrict__ bhh,
                            const float* __restrict__ bsel,
                            float* __restrict__ out) {
  int i = blockIdx.x * 256 + threadIdx.x;      // 65536
  if (i < B_ * H_) g_h64[i] = 0.0;
  if (i < B_ * F_) {
    int b = i >> 9, f = i & 511;
    g_ci64[i] = (double)x[(size_t)b * (T_ * F_) + f];   // t=0: curr_in = x_0
    out[(size_t)SEL_OFF + i] = 1.0f;                    // sel_weights[0] = ones
  }
  if (i < H_) {
    g_br[i] = (double)bih[i] + (double)bhh[i];
    g_bz[i] = (double)bih[H_ + i] + (double)bhh[H_ + i];
    g_bi[i] = (double)bih[2 * H_ + i];
    g_bh[i] = (double)bhh[2 * H_ + i];
  }
  if (i < F_) g_bsel[i] = (double)bsel[i];
  if (i < 128) g_bar8[i] = 0u;
  if (i == 0) g_selcnt = 0u;
}

// ---------------- grid barrier: 8 padded counters, explicit vm drain, no fences ----
__device__ __forceinline__ void gridbar(int bid, unsigned tgt) {
  __builtin_amdgcn_s_waitcnt(0);    // each thread drains its own sc1 stores
  __syncthreads();
  if (threadIdx.x == 0)
    __hip_atomic_fetch_add(&g_bar8[(bid & 7) * 16], 1u,
                           __ATOMIC_RELAXED, __HIP_MEMORY_SCOPE_AGENT);
  if (threadIdx.x < 8) {
    while (__hip_atomic_load(&g_bar8[threadIdx.x * 16],
                             __ATOMIC_RELAXED, __HIP_MEMORY_SCOPE_AGENT) < tgt)
      __builtin_amdgcn_s_sleep(1);
  }
  __syncthreads();
}

// ---------------- persistent time-loop kernel ----------------
// 256 blocks x 1024 thr, 1 block/CU (LDS 123 KB). block = (jjc, bb):
//   jjc = (bid&7)*4 + ((bid>>3)&3)  -> same-XCD blocks share 4 jj-chunks (L2 weight residency)
//   bb  = bid>>5
// Block owns output cells (32 jj) x (8 b), FULL K — no split-K partial exchange.
__global__ __launch_bounds__(NTHR, 4) void k_persist(const float* __restrict__ x,
                                                     const float* __restrict__ u,
                                                     float* __restrict__ out) {
  __shared__ double lds[LDS_N];
  const int tid = threadIdx.x;
  const int bid = blockIdx.x;
  const int jjc = (bid & 7) * 4 + ((bid >> 3) & 3);
  const int bb  = bid >> 5;
  const int jj0 = jjc << 5;
  const int f0  = jjc << 4;
  const int b0  = bb << 3;

  // G decode: wave w = k-slice owner; lanes: b4 (2 b-halves) x jjl (32)
  const int w    = tid >> 6;          // 0..15
  const int lane = tid & 63;
  const int b4   = lane >> 5;         // 0,1
  const int jjl  = lane & 31;
  const int jj   = jj0 + jjl;

  // L decode: (lkq 8) x (lbl 8) x (lfl 16)
  const int lkq = tid >> 7;
  const int lbl = (tid >> 4) & 7;
  const int lfl = tid & 15;
  const int lf  = f0 + lfl;

  unsigned nbar = 0;

  for (int t = 0; t < T_; ++t) {
    // ---- stage h(t-1): 8 b x 1024 k -> lds[AH + k*10 + bl]
    #pragma unroll
    for (int it = 0; it < 8; ++it) {
      int e = it * 1024 + tid;
      int bl = e & 7, k = e >> 3;
      lds[AH + k * 10 + bl] = ld_c(&g_h64[(size_t)(b0 + bl) * H_ + k]);
    }
    __syncthreads();

    // ---- L: logits(h(t-1)) -> mask, ci(t), sel_weights[t]
    if (t > 0) {
      double acc = 0.0;
      const int k0 = lkq << 7;
      #pragma unroll 4
      for (int ki = 0; ki < 128; ++ki) {
        int k = k0 + ki;
        acc = fma(lds[AH + k * 10 + lbl], g_wselT[(size_t)k * F_ + lf], acc);
      }
      lds[ACI + tid & 0 ? 0 : (ACI + lkq * 128 + lbl * 16 + lfl)] = acc; // lred in ACI region
      __syncthreads();
      bool wflag = false;
      if (tid < 128) {
        double s = 0.0;
        #pragma unroll
        for (int q = 0; q < 8; ++q) s += lds[ACI + q * 128 + tid];
        int fl2 = tid & 15, bl2 = tid >> 4;
        int ff = f0 + fl2, bq = b0 + bl2;
        double logit = s + g_bsel[ff];
        double sig = 1.0 / (1.0 + exp(-logit));
        float uv = u[(size_t)(t * B_ + bq) * F_ + ff];
        wflag = sig > (double)uv;
        out[(size_t)SEL_OFF + (size_t)(t * B_ + bq) * F_ + ff] = wflag ? 1.0f : 0.0f;
        st_c(&g_ci64[(size_t)bq * F_ + ff],
             wflag ? (double)x[(size_t)(bq * T_ + t) * F_ + ff] : 0.0);
      }
      unsigned long long bal = __ballot(wflag);
      if (tid < 128 && (tid & 63) == 0)
        atomicAdd(&g_selcnt, (unsigned)__popcll(bal));
    }

    gridbar(bid, ++nbar * 32u);   // barrier B: ci(t) visible everywhere

    // ---- stage ci(t): 8 b x 512 k -> lds[ACI + k*10 + bl]
    #pragma unroll
    for (int it = 0; it < 4; ++it) {
      int e = it * 1024 + tid;
      int bl = e & 7, k = e >> 3;
      lds[ACI + k * 10 + bl] = ld_c(&g_ci64[(size_t)(b0 + bl) * F_ + k]);
    }
    __syncthreads();

    // ---- G: full-K gates for (32 jj x 8 b); wave w owns k-slice, one weight read per k
    double acc[4][4];   // [ch: r,z,in,hn][bi]
    #pragma unroll
    for (int c = 0; c < 4; ++c)
      #pragma unroll
      for (int q = 0; q < 4; ++q) acc[c][q] = 0.0;

    {
      const int kci0 = w << 5;           // 32 ci k's per wave
      const float2* wrzp = &g_Wrz[(size_t)kci0 * 1024 + jj];
      const float*  wnp  = &g_Wn [(size_t)kci0 * 1024 + jj];
      #pragma unroll 4
      for (int ki = 0; ki < 32; ++ki) {
        float2 wf = wrzp[(size_t)ki * 1024];
        float  nf = wnp [(size_t)ki * 1024];
        double wr = (double)wf.x, wz = (double)wf.y, wn = (double)nf;
        const double* ap = &lds[ACI + (kci0 + ki) * 10 + b4 * 4];
        double a0 = ap[0], a1 = ap[1], a2 = ap[2], a3 = ap[3];
        acc[0][0] = fma(a0, wr, acc[0][0]); acc[1][0] = fma(a0, wz, acc[1][0]); acc[2][0] = fma(a0, wn, acc[2][0]);
        acc[0][1] = fma(a1, wr, acc[0][1]); acc[1][1] = fma(a1, wz, acc[1][1]); acc[2][1] = fma(a1, wn, acc[2][1]);
        acc[0][2] = fma(a2, wr, acc[0][2]); acc[1][2] = fma(a2, wz, acc[1][2]); acc[2][2] = fma(a2, wn, acc[2][2]);
        acc[0][3] = fma(a3, wr, acc[0][3]); acc[1][3] = fma(a3, wz, acc[1][3]); acc[2][3] = fma(a3, wn, acc[2][3]);
      }
    }
    {
      const int kh0 = w << 6;            // 64 h k's per wave
      const float2* wrzp = &g_Wrz[(size_t)(512 + kh0) * 1024 + jj];
      const float*  wnp  = &g_Wn [(size_t)(512 + kh0) * 1024 + jj];
      #pragma unroll 4
      for (int ki = 0; ki < 64; ++ki) {
        float2 wf = wrzp[(size_t)ki * 1024];
        float  nf = wnp [(size_t)ki * 1024];
        double wr = (double)wf.x, wz = (double)wf.y, wn = (double)nf;
        const double* ap = &lds[AH + (kh0 + ki) * 10 + b4 * 4];
        double a0 = ap[0], a1 = ap[1], a2 = ap[2], a3 = ap[3];
        acc[0][0] = fma(a0, wr, acc[0][0]); acc[1][0] = fma(a0, wz, acc[1][0]); acc[3][0] = fma(a0, wn, acc[3][0]);
        acc[0][1] = fma(a1, wr, acc[0][1]); acc[1][1] = fma(a1, wz, acc[1][1]); acc[3][1] = fma(a1, wn, acc[3][1]);
        acc[0][2] = fma(a2, wr, acc[0][2]); acc[1][2] = fma(a2, wz, acc[1][2]); acc[3][2] = fma(a2, wn, acc[3][2]);
        acc[0][3] = fma(a3, wr, acc[0][3]); acc[1][3] = fma(a3, wz, acc[1][3]); acc[3][3] = fma(a3, wn, acc[3][3]);
      }
    }

    __syncthreads();   // act reads done; LDS becomes reduction buffer

    // ---- 4-round tree reduce over the 16 k-slice waves
    #pragma unroll
    for (int half = 8; half >= 1; half >>= 1) {
      if (w >= half && w < 2 * half) {
        #pragma unroll
        for (int c = 0; c < 4; ++c)
          #pragma unroll
          for (int q = 0; q < 4; ++q)
            lds[((w - half) * 4 + c) * 256 + (b4 * 4 + q) * 32 + jjl] = acc[c][q];
      }
      __syncthreads();
      if (w < half) {
        #pragma unroll
        for (int c = 0; c < 4; ++c)
          #pragma unroll
          for (int q = 0; q < 4; ++q)
            acc[c][q] += lds[(w * 4 + c) * 256 + (b4 * 4 + q) * 32 + jjl];
      }
      __syncthreads();
    }

    // ---- GRU update on wave 0 (holds full sums for all 8 b x 32 jj)
    if (w == 0) {
      double br = g_br[jj], bz = g_bz[jj], bi = g_bi[jj], bh = g_bh[jj];
      #pragma unroll
      for (int q = 0; q < 4; ++q) {
        int b = b4 * 4 + q;
        double sr = acc[0][q] + br;
        double sz = acc[1][q] + bz;
        double si = acc[2][q] + bi;
        double sh = acc[3][q] + bh;
        double r = 1.0 / (1.0 + exp(-sr));
        double z = 1.0 / (1.0 + exp(-sz));
        double n = tanh(si + r * sh);
        double hold = ld_c(&g_h64[(size_t)(b0 + b) * H_ + jj]);
        double hnew = (1.0 - z) * n + z * hold;
        st_c(&g_h64[(size_t)(b0 + b) * H_ + jj], hnew);
        g_hist[(size_t)t * (B_ * H_) + (size_t)(b0 + b) * H_ + jj] = (float)hnew;
      }
    }

    gridbar(bid, ++nbar * 32u);   // barrier A: h(t) visible
  }
}

// ---------------- batched out-GEMM (f32) ----------------
__global__ __launch_bounds__(256) void k_out(const float* __restrict__ Wo,
                                             const float* __restrict__ bo,
                                             float* __restrict__ out) {
  __shared__ float sA[32][68];
  __shared__ float sB[32][68];
  const int tid = threadIdx.x;
  const int to = tid & 15, tm = tid >> 4;
  const int m0 = blockIdx.y * 64, o0 = blockIdx.x * 64;
  if (blockIdx.x == 0 && blockIdx.y == 0 && tid == 0)
    out[NSEL_IX] = (float)g_selcnt;
  float acc[4][4] = {{0.f}};
  for (int kt = 0; kt < 1024 / 32; ++kt) {
    #pragma unroll
    for (int it = 0; it < 8; ++it) {
      int e  = it * 256 + tid;
      int rl = e >> 5, kl = e & 31;
      sA[kl][rl] = g_hist[(size_t)(m0 + rl) * H_ + kt * 32 + kl];
      sB[kl][rl] = Wo[(size_t)(o0 + rl) * H_ + kt * 32 + kl];
    }
    __syncthreads();
    #pragma unroll
    for (int kl = 0; kl < 32; ++kl) {
      float a[4], bv[4];
      #pragma unroll
      for (int i = 0; i < 4; ++i) a[i] = sA[kl][tm * 4 + i];
      #pragma unroll
      for (int i = 0; i < 4; ++i) bv[i] = sB[kl][to * 4 + i];
      #pragma unroll
      for (int i = 0; i < 4; ++i)
        #pragma unroll
        for (int c = 0; c < 4; ++c)
          acc[i][c] = fmaf(a[i], bv[c], acc[i][c]);
    }
    __syncthreads();
  }
  #pragma unroll
  for (int i = 0; i < 4; ++i) {
    int m = m0 + tm * 4 + i;
    #pragma unroll
    for (int c = 0; c < 4; ++c) {
      int o = o0 + to * 4 + c;
      out[(size_t)m * O_ + o] = acc[i][c] + bo[o];
    }
  }
}

// ---------------- launcher ----------------
extern "C" void kernel_launch(void* const* d_in, const int* in_sizes, int n_in,
                              void* d_out, int out_size, void* d_ws, size_t ws_size,
                              hipStream_t stream) {
  (void)in_sizes; (void)n_in; (void)out_size; (void)d_ws; (void)ws_size;
  const float* x     = (const float*)d_in[0];
  const float* u     = (const float*)d_in[1];
  const float* W_ih  = (const float*)d_in[2];
  const float* b_ih  = (const float*)d_in[3];
  const float* W_hh  = (const float*)d_in[4];
  const float* b_hh  = (const float*)d_in[5];
  const float* W_out = (const float*)d_in[6];
  const float* b_out = (const float*)d_in[7];
  const float* W_sel = (const float*)d_in[8];
  const float* b_sel = (const float*)d_in[9];
  float* out = (float*)d_out;

  k_prep_w   <<<6144, 256, 0, stream>>>(W_ih, W_hh);
  k_prep_wsel<<<2048, 256, 0, stream>>>(W_sel);
  k_prep_misc<<<256, 256, 0, stream>>>(x, b_ih, b_hh, b_sel, out);

  k_persist<<<NBLK, NTHR, 0, stream>>>(x, u, out);

  k_out<<<dim3(8, 256), 256, 0, stream>>>(W_out, b_out, out);
}

// Round 6
// 22678.535 us; speedup vs baseline: 1.9854x; 1.1239x over previous
//
#include <hip/hip_runtime.h>

#define B_ 64
#define T_ 256
#define F_ 512
#define H_ 1024
#define O_ 512
#define NBLK 256
#define NTHR 1024

#define OUT_N   (T_ * B_ * O_)        /* 8388608 */
#define NSEL_IX OUT_N
#define SEL_OFF (OUT_N + 1)

// LDS map (doubles): [b][k] layouts, padded strides
#define ACI 0                 /* ci tile  [8][520]  */
#define AH  4160              /* h tile   [8][1032] */
#define LDS_N 12416           /* 99.3 KB -> 1 block/CU */

// ---------------- device state ----------------
__device__ float2 g_Wrz[(size_t)1536 * 1024];   // [k][jj] (r,z) f32, 12.6 MB
__device__ float  g_Wn [(size_t)1536 * 1024];   // [k][jj] n f32,     6.3 MB
__device__ double g_wselT[(size_t)H_ * F_];     // [k][f] f64,        4.2 MB
__device__ double g_br[H_], g_bz[H_], g_bi[H_], g_bh[H_];
__device__ double g_bsel[F_];
__device__ double g_h64[B_ * H_];               // sc1 traffic (f64 exact)
__device__ unsigned g_mask[B_ * 32];            // Bernoulli masks: u32 holds 16 f-bits
__device__ float  g_hist[(size_t)T_ * B_ * H_]; // h history f32, 67 MB
__device__ unsigned g_selcnt;
// hierarchical barrier state (all padded to separate 256B lines)
__device__ unsigned g_grp[8 * 64];
__device__ unsigned g_go [8 * 64];
__device__ unsigned g_root[64];

// ---------------- coherent access helpers ----------------
__device__ __forceinline__ double ld_c(const double* p) {
  return __hip_atomic_load(p, __ATOMIC_RELAXED, __HIP_MEMORY_SCOPE_AGENT);
}
__device__ __forceinline__ void st_c(double* p, double v) {
  __hip_atomic_store(p, v, __ATOMIC_RELAXED, __HIP_MEMORY_SCOPE_AGENT);
}
__device__ __forceinline__ unsigned ld_cu(const unsigned* p) {
  return __hip_atomic_load(p, __ATOMIC_RELAXED, __HIP_MEMORY_SCOPE_AGENT);
}
__device__ __forceinline__ void st_cu(unsigned* p, unsigned v) {
  __hip_atomic_store(p, v, __ATOMIC_RELAXED, __HIP_MEMORY_SCOPE_AGENT);
}

// ---------------- prep ----------------
__global__ void k_prep_w(const float* __restrict__ Wih, const float* __restrict__ Whh) {
  int i = blockIdx.x * 256 + threadIdx.x;      // 1536*1024
  int k = i >> 10, jj = i & 1023;
  float r, z, n;
  if (k < 512) {
    r = Wih[(size_t)jj * F_ + k];
    z = Wih[(size_t)(H_ + jj) * F_ + k];
    n = Wih[(size_t)(2 * H_ + jj) * F_ + k];
  } else {
    int kk = k - 512;
    r = Whh[(size_t)jj * H_ + kk];
    z = Whh[(size_t)(H_ + jj) * H_ + kk];
    n = Whh[(size_t)(2 * H_ + jj) * H_ + kk];
  }
  g_Wrz[i] = make_float2(r, z);
  g_Wn[i]  = n;
}
__global__ void k_prep_wsel(const float* __restrict__ W) {  // W_sel [F, H]
  int i = blockIdx.x * 256 + threadIdx.x;      // 1024*512
  int k = i >> 9, f = i & 511;
  g_wselT[i] = (double)W[(size_t)f * H_ + k];
}
__global__ void k_prep_misc(const float* __restrict__ bih,
                            const float* __restrict__ bhh,
                            const float* __restrict__ bsel,
                            float* __restrict__ out) {
  int i = blockIdx.x * 256 + threadIdx.x;      // 65536
  if (i < B_ * H_) g_h64[i] = 0.0;
  if (i < B_ * F_) out[(size_t)SEL_OFF + i] = 1.0f;   // sel_weights[0] = ones
  if (i < B_ * 32) g_mask[i] = 0xFFFFu;               // t=0: select everything
  if (i < H_) {
    g_br[i] = (double)bih[i] + (double)bhh[i];
    g_bz[i] = (double)bih[H_ + i] + (double)bhh[H_ + i];
    g_bi[i] = (double)bih[2 * H_ + i];
    g_bh[i] = (double)bhh[2 * H_ + i];
  }
  if (i < F_) g_bsel[i] = (double)bsel[i];
  if (i < 8 * 64) { g_grp[i] = 0u; g_go[i] = 0u; }
  if (i < 64) g_root[i] = 0u;
  if (i == 0) g_selcnt = 0u;
}

// ---------------- hierarchical grid barrier (contention-safe) ----------------
// group g = bid&7 (32 blocks); leader = block g. Chain:
//   all: add g_grp[g]  ->  leader: spin g_grp[g]==32*ep, add root, spin root==8*ep,
//   store g_go[g]=ep   ->  followers: spin g_go[g] >= ep (long backoff, 31/line).
__device__ __forceinline__ void gridbar(int bid, unsigned ep) {
  __builtin_amdgcn_s_waitcnt(0);     // drain this thread's sc1 stores
  __syncthreads();                   // all threads' stores drained
  if (threadIdx.x == 0) {
    const int g = bid & 7;
    __hip_atomic_fetch_add(&g_grp[g * 64], 1u, __ATOMIC_RELAXED, __HIP_MEMORY_SCOPE_AGENT);
    if (bid < 8) {
      while (ld_cu(&g_grp[g * 64]) < ep * 32u) __builtin_amdgcn_s_sleep(2);
      __hip_atomic_fetch_add(&g_root[0], 1u, __ATOMIC_RELAXED, __HIP_MEMORY_SCOPE_AGENT);
      while (ld_cu(&g_root[0]) < ep * 8u) __builtin_amdgcn_s_sleep(2);
      st_cu(&g_go[g * 64], ep);
    } else {
      while (ld_cu(&g_go[g * 64]) < ep) __builtin_amdgcn_s_sleep(8);
    }
  }
  __syncthreads();
}

// ---------------- persistent time-loop kernel ----------------
// 256 blocks x 1024 thr, 1 block/CU (LDS 99.3 KB). block = (jjc, bb):
//   jjc = (bid&7)*4 + ((bid>>3)&3)  -> XCD-pinned weight columns (L2 residency)
//   bb  = bid>>5
// Block owns (32 jj) x (8 b) output cells, FULL K. No split-K exchange.
__global__ __launch_bounds__(NTHR, 4) void k_persist(const float* __restrict__ x,
                                                     const float* __restrict__ u,
                                                     float* __restrict__ out) {
  __shared__ double lds[LDS_N];
  const int tid = threadIdx.x;
  const int bid = blockIdx.x;
  const int jjc = (bid & 7) * 4 + ((bid >> 3) & 3);
  const int bb  = bid >> 5;
  const int jj0 = jjc << 5;
  const int f0  = jjc << 4;
  const int b0  = bb << 3;

  // G decode: wave w = k-slice; lanes: b4 (2 b-halves) x jjl (32)
  const int w    = tid >> 6;          // 0..15
  const int lane = tid & 63;
  const int b4   = lane >> 5;         // 0,1
  const int jjl  = lane & 31;
  const int jj   = jj0 + jjl;

  // L decode: (lkq 8) x (lbl 8) x (lfl 16)
  const int lkq = tid >> 7;
  const int lbl = (tid >> 4) & 7;
  const int lfl = tid & 15;
  const int lf  = f0 + lfl;

  unsigned nbar = 0;

  for (int t = 0; t < T_; ++t) {
    // ---- stage h(t-1): [bl][k] coalesced (512B/wave), conflict-free ds_write
    #pragma unroll
    for (int it = 0; it < 8; ++it) {
      int e = it * 1024 + tid;
      int bl = e >> 10, k = e & 1023;
      lds[AH + bl * 1032 + k] = ld_c(&g_h64[(size_t)(b0 + bl) * H_ + k]);
    }
    __syncthreads();

    // ---- L: logits(h(t-1)) -> mask bits, sel_weights[t]
    if (t > 0) {
      double acc = 0.0;
      const int k0 = lkq << 7;
      const double* hrow = &lds[AH + lbl * 1032 + k0];
      const double* wp = &g_wselT[(size_t)k0 * F_ + lf];
      #pragma unroll 4
      for (int ki = 0; ki < 128; ++ki) {
        acc = fma(hrow[ki], wp[0], acc);
        wp += F_;
      }
      lds[lkq * 128 + lbl * 16 + lfl] = acc;
      __syncthreads();
      bool wflag = false;
      if (tid < 128) {
        double s = 0.0;
        #pragma unroll
        for (int q = 0; q < 8; ++q) s += lds[q * 128 + tid];
        int fl2 = tid & 15, bl2 = tid >> 4;
        int ff = f0 + fl2, bq = b0 + bl2;
        double logit = s + g_bsel[ff];
        double sig = 1.0 / (1.0 + exp(-logit));
        float uv = u[(size_t)(t * B_ + bq) * F_ + ff];
        wflag = sig > (double)uv;
        out[(size_t)SEL_OFF + (size_t)(t * B_ + bq) * F_ + ff] = wflag ? 1.0f : 0.0f;
      }
      unsigned long long bal = __ballot(wflag);
      if (tid < 128) {
        if ((tid & 15) == 0)
          st_cu(&g_mask[(size_t)(b0 + (tid >> 4)) * 32 + jjc],
                (unsigned)((bal >> (tid & 48)) & 0xFFFFull));
        if ((tid & 63) == 0)
          atomicAdd(&g_selcnt, (unsigned)__popcll(bal));
      }
      __syncthreads();
    }

    gridbar(bid, ++nbar);   // barrier B: all masks(t) visible

    // ---- stage ci(t) from mask bits x plain-cached x: [bl][k]
    #pragma unroll
    for (int it = 0; it < 4; ++it) {
      int e = it * 1024 + tid;
      int bl = e >> 9, k = e & 511;
      unsigned m = ld_cu(&g_mask[(size_t)(b0 + bl) * 32 + (k >> 4)]);
      double xd = (double)x[((size_t)(b0 + bl) * T_ + t) * F_ + k];
      lds[ACI + bl * 520 + k] = ((m >> (k & 15)) & 1u) ? xd : 0.0;
    }
    __syncthreads();

    // ---- G: full-K gates for (32 jj x 8 b); wave w owns k-slice
    double acc[4][4];   // [ch: r,z,in,hn][b]
    #pragma unroll
    for (int c = 0; c < 4; ++c)
      #pragma unroll
      for (int q = 0; q < 4; ++q) acc[c][q] = 0.0;

    {
      const int kci0 = w << 5;           // 32 ci k's per wave
      const float2* wrzp = &g_Wrz[(size_t)kci0 * 1024 + jj];
      const float*  wnp  = &g_Wn [(size_t)kci0 * 1024 + jj];
      const double* ap0  = &lds[ACI + (b4 * 4) * 520 + kci0];
      #pragma unroll 4
      for (int ki = 0; ki < 32; ++ki) {
        float2 wf = wrzp[(size_t)ki * 1024];
        float  nf = wnp [(size_t)ki * 1024];
        double wr = (double)wf.x, wz = (double)wf.y, wn = (double)nf;
        double a0 = ap0[ki], a1 = ap0[520 + ki], a2 = ap0[1040 + ki], a3 = ap0[1560 + ki];
        acc[0][0] = fma(a0, wr, acc[0][0]); acc[1][0] = fma(a0, wz, acc[1][0]); acc[2][0] = fma(a0, wn, acc[2][0]);
        acc[0][1] = fma(a1, wr, acc[0][1]); acc[1][1] = fma(a1, wz, acc[1][1]); acc[2][1] = fma(a1, wn, acc[2][1]);
        acc[0][2] = fma(a2, wr, acc[0][2]); acc[1][2] = fma(a2, wz, acc[1][2]); acc[2][2] = fma(a2, wn, acc[2][2]);
        acc[0][3] = fma(a3, wr, acc[0][3]); acc[1][3] = fma(a3, wz, acc[1][3]); acc[2][3] = fma(a3, wn, acc[2][3]);
      }
    }
    {
      const int kh0 = w << 6;            // 64 h k's per wave
      const float2* wrzp = &g_Wrz[(size_t)(512 + kh0) * 1024 + jj];
      const float*  wnp  = &g_Wn [(size_t)(512 + kh0) * 1024 + jj];
      const double* ap0  = &lds[AH + (b4 * 4) * 1032 + kh0];
      #pragma unroll 4
      for (int ki = 0; ki < 64; ++ki) {
        float2 wf = wrzp[(size_t)ki * 1024];
        float  nf = wnp [(size_t)ki * 1024];
        double wr = (double)wf.x, wz = (double)wf.y, wn = (double)nf;
        double a0 = ap0[ki], a1 = ap0[1032 + ki], a2 = ap0[2064 + ki], a3 = ap0[3096 + ki];
        acc[0][0] = fma(a0, wr, acc[0][0]); acc[1][0] = fma(a0, wz, acc[1][0]); acc[3][0] = fma(a0, wn, acc[3][0]);
        acc[0][1] = fma(a1, wr, acc[0][1]); acc[1][1] = fma(a1, wz, acc[1][1]); acc[3][1] = fma(a1, wn, acc[3][1]);
        acc[0][2] = fma(a2, wr, acc[0][2]); acc[1][2] = fma(a2, wz, acc[1][2]); acc[3][2] = fma(a2, wn, acc[3][2]);
        acc[0][3] = fma(a3, wr, acc[0][3]); acc[1][3] = fma(a3, wz, acc[1][3]); acc[3][3] = fma(a3, wn, acc[3][3]);
      }
    }

    __syncthreads();   // act tiles dead; LDS becomes reduction buffer

    // ---- 4-round tree reduce over the 16 k-slice waves
    #pragma unroll
    for (int half = 8; half >= 1; half >>= 1) {
      if (w >= half && w < 2 * half) {
        #pragma unroll
        for (int c = 0; c < 4; ++c)
          #pragma unroll
          for (int q = 0; q < 4; ++q)
            lds[((w - half) * 4 + c) * 256 + (b4 * 4 + q) * 32 + jjl] = acc[c][q];
      }
      __syncthreads();
      if (w < half) {
        #pragma unroll
        for (int c = 0; c < 4; ++c)
          #pragma unroll
          for (int q = 0; q < 4; ++q)
            acc[c][q] += lds[(w * 4 + c) * 256 + (b4 * 4 + q) * 32 + jjl];
      }
      __syncthreads();
    }

    // ---- GRU update on wave 0
    if (w == 0) {
      double br = g_br[jj], bz = g_bz[jj], bi = g_bi[jj], bh = g_bh[jj];
      #pragma unroll
      for (int q = 0; q < 4; ++q) {
        int b = b4 * 4 + q;
        double sr = acc[0][q] + br;
        double sz = acc[1][q] + bz;
        double si = acc[2][q] + bi;
        double sh = acc[3][q] + bh;
        double r = 1.0 / (1.0 + exp(-sr));
        double z = 1.0 / (1.0 + exp(-sz));
        double n = tanh(si + r * sh);
        double hold = ld_c(&g_h64[(size_t)(b0 + b) * H_ + jj]);
        double hnew = (1.0 - z) * n + z * hold;
        st_c(&g_h64[(size_t)(b0 + b) * H_ + jj], hnew);
        g_hist[(size_t)t * (B_ * H_) + (size_t)(b0 + b) * H_ + jj] = (float)hnew;
      }
    }

    gridbar(bid, ++nbar);   // barrier A: h(t) visible
  }
}

// ---------------- batched out-GEMM (f32) ----------------
__global__ __launch_bounds__(256) void k_out(const float* __restrict__ Wo,
                                             const float* __restrict__ bo,
                                             float* __restrict__ out) {
  __shared__ float sA[32][68];
  __shared__ float sB[32][68];
  const int tid = threadIdx.x;
  const int to = tid & 15, tm = tid >> 4;
  const int m0 = blockIdx.y * 64, o0 = blockIdx.x * 64;
  if (blockIdx.x == 0 && blockIdx.y == 0 && tid == 0)
    out[NSEL_IX] = (float)g_selcnt;
  float acc[4][4] = {{0.f}};
  for (int kt = 0; kt < 1024 / 32; ++kt) {
    #pragma unroll
    for (int it = 0; it < 8; ++it) {
      int e  = it * 256 + tid;
      int rl = e >> 5, kl = e & 31;
      sA[kl][rl] = g_hist[(size_t)(m0 + rl) * H_ + kt * 32 + kl];
      sB[kl][rl] = Wo[(size_t)(o0 + rl) * H_ + kt * 32 + kl];
    }
    __syncthreads();
    #pragma unroll
    for (int kl = 0; kl < 32; ++kl) {
      float a[4], bv[4];
      #pragma unroll
      for (int i = 0; i < 4; ++i) a[i] = sA[kl][tm * 4 + i];
      #pragma unroll
      for (int i = 0; i < 4; ++i) bv[i] = sB[kl][to * 4 + i];
      #pragma unroll
      for (int i = 0; i < 4; ++i)
        #pragma unroll
        for (int c = 0; c < 4; ++c)
          acc[i][c] = fmaf(a[i], bv[c], acc[i][c]);
    }
    __syncthreads();
  }
  #pragma unroll
  for (int i = 0; i < 4; ++i) {
    int m = m0 + tm * 4 + i;
    #pragma unroll
    for (int c = 0; c < 4; ++c) {
      int o = o0 + to * 4 + c;
      out[(size_t)m * O_ + o] = acc[i][c] + bo[o];
    }
  }
}

// ---------------- launcher ----------------
extern "C" void kernel_launch(void* const* d_in, const int* in_sizes, int n_in,
                              void* d_out, int out_size, void* d_ws, size_t ws_size,
                              hipStream_t stream) {
  (void)in_sizes; (void)n_in; (void)out_size; (void)d_ws; (void)ws_size;
  const float* x     = (const float*)d_in[0];
  const float* u     = (const float*)d_in[1];
  const float* W_ih  = (const float*)d_in[2];
  const float* b_ih  = (const float*)d_in[3];
  const float* W_hh  = (const float*)d_in[4];
  const float* b_hh  = (const float*)d_in[5];
  const float* W_out = (const float*)d_in[6];
  const float* b_out = (const float*)d_in[7];
  const float* W_sel = (const float*)d_in[8];
  const float* b_sel = (const float*)d_in[9];
  float* out = (float*)d_out;

  k_prep_w   <<<6144, 256, 0, stream>>>(W_ih, W_hh);
  k_prep_wsel<<<2048, 256, 0, stream>>>(W_sel);
  k_prep_misc<<<256, 256, 0, stream>>>(b_ih, b_hh, b_sel, out);

  k_persist<<<NBLK, NTHR, 0, stream>>>(x, u, out);

  k_out<<<dim3(8, 256), 256, 0, stream>>>(W_out, b_out, out);
}